// Round 1
// baseline (880.139 us; speedup 1.0000x reference)
//
#include <hip/hip_runtime.h>
#include <math.h>

#define N_NODES 100000
#define N_EDGES 1600000
#define F_OUT 64

// ---------------------------------------------------------------- degree ----
__global__ __launch_bounds__(256) void k_init_deg(float* deg) {
    int i = blockIdx.x * 256 + threadIdx.x;
    if (i < N_NODES) deg[i] = 1.0f;  // self-loop contributes 1 to every node
}

__global__ __launch_bounds__(256) void k_count_deg(const int* __restrict__ dst, float* deg) {
    int e = blockIdx.x * 256 + threadIdx.x;
    if (e < N_EDGES) atomicAdd(&deg[dst[e]], 1.0f);
}

__global__ __launch_bounds__(256) void k_dinv(float* deg) {
    int i = blockIdx.x * 256 + threadIdx.x;
    if (i < N_NODES) deg[i] = 1.0f / sqrtf(deg[i]);  // deg >= 1 always
}

// ---------------------------------------------------------------- GEMM ------
// H[16 rows x 64 cols] per block; 256 threads; each thread does 4 rows x 1 col.
// N_NODES = 100000 = 6250 * 16 exactly -> no row bounds checks.
template <int FIN>
__global__ __launch_bounds__(256) void k_gemm(const float* __restrict__ X,
                                              const float* __restrict__ W,
                                              float* __restrict__ H) {
    __shared__ float sW[FIN * 64];
    __shared__ float sx[16 * FIN];
    // stage W (FIN x 64) via float4: FIN*16 vectors
    {
        const float4* Wv = (const float4*)W;
        float4* sWv = (float4*)sW;
        #pragma unroll
        for (int i = threadIdx.x; i < FIN * 16; i += 256) sWv[i] = Wv[i];
    }
    // stage 16 contiguous rows of X: 16*FIN floats = 4*FIN float4
    {
        const float4* Xv = (const float4*)(X + (size_t)blockIdx.x * 16 * FIN);
        float4* sxv = (float4*)sx;
        #pragma unroll
        for (int i = threadIdx.x; i < 4 * FIN; i += 256) sxv[i] = Xv[i];
    }
    __syncthreads();

    const int col = threadIdx.x & 63;
    const int rg  = threadIdx.x >> 6;  // 0..3 -> rows rg*4 .. rg*4+3
    float a0 = 0.f, a1 = 0.f, a2 = 0.f, a3 = 0.f;
    #pragma unroll
    for (int k = 0; k < FIN; ++k) {
        const float w = sW[k * 64 + col];
        a0 += sx[(rg * 4 + 0) * FIN + k] * w;
        a1 += sx[(rg * 4 + 1) * FIN + k] * w;
        a2 += sx[(rg * 4 + 2) * FIN + k] * w;
        a3 += sx[(rg * 4 + 3) * FIN + k] * w;
    }
    size_t base = (size_t)blockIdx.x * 16 * 64 + (size_t)rg * 4 * 64 + col;
    H[base +   0] = a0;
    H[base +  64] = a1;
    H[base + 128] = a2;
    H[base + 192] = a3;
}

// --------------------------------------------------- agg init (self + bias) -
// agg[n][f] = H[n][f] * dinv[n]^2 + b[f]; float4 over N*16 vectors.
__global__ __launch_bounds__(256) void k_init_agg(const float* __restrict__ H,
                                                  const float* __restrict__ dinv,
                                                  const float* __restrict__ b,
                                                  float* __restrict__ agg) {
    int i = blockIdx.x * 256 + threadIdx.x;  // < N_NODES*16
    int n = i >> 4;
    int f4 = i & 15;
    float di = dinv[n];
    float s = di * di;
    float4 h = ((const float4*)H)[i];
    float4 bb = ((const float4*)b)[f4];
    float4 r;
    r.x = h.x * s + bb.x;
    r.y = h.y * s + bb.y;
    r.z = h.z * s + bb.z;
    r.w = h.w * s + bb.w;
    ((float4*)agg)[i] = r;
}

// ---------------------------------------------------------------- scatter ---
// One 64-lane wave per edge: gather H[src]*norm, atomicAdd into agg[dst].
__global__ __launch_bounds__(256) void k_scatter(const float* __restrict__ H,
                                                 const int* __restrict__ src,
                                                 const int* __restrict__ dst,
                                                 const float* __restrict__ dinv,
                                                 float* __restrict__ agg) {
    long long idx = (long long)blockIdx.x * 256 + threadIdx.x;
    int e = (int)(idx >> 6);            // wave-uniform
    int lane = threadIdx.x & 63;
    int s = src[e];
    int d = dst[e];
    float m = dinv[s] * dinv[d];
    float v = H[(size_t)s * 64 + lane] * m;
    atomicAdd(&agg[(size_t)d * 64 + lane], v);
}

// ---------------------------------------------------------------- GELU ------
__global__ __launch_bounds__(256) void k_gelu(const float* __restrict__ A,
                                              float* __restrict__ O) {
    int i = blockIdx.x * 256 + threadIdx.x;  // < N_NODES*16 float4s
    float4 v = ((const float4*)A)[i];
    float4 r;
    r.x = 0.5f * v.x * (1.0f + erff(v.x * 0.70710678118654752f));
    r.y = 0.5f * v.y * (1.0f + erff(v.y * 0.70710678118654752f));
    r.z = 0.5f * v.z * (1.0f + erff(v.z * 0.70710678118654752f));
    r.w = 0.5f * v.w * (1.0f + erff(v.w * 0.70710678118654752f));
    ((float4*)O)[i] = r;
}

// ---------------------------------------------------------------- launch ----
extern "C" void kernel_launch(void* const* d_in, const int* in_sizes, int n_in,
                              void* d_out, int out_size, void* d_ws, size_t ws_size,
                              hipStream_t stream) {
    const float* x  = (const float*)d_in[0];
    const int* edge = (const int*)d_in[1];           // [2, N_EDGES] int32
    const float* W1 = (const float*)d_in[2];
    const float* b1 = (const float*)d_in[3];
    const float* W2 = (const float*)d_in[4];
    const float* b2 = (const float*)d_in[5];
    float* out = (float*)d_out;                      // [N_NODES, 64]

    const int* src = edge;
    const int* dst = edge + N_EDGES;

    float* ws   = (float*)d_ws;
    float* dinv = ws;                  // N_NODES floats (also deg scratch)
    float* hA   = ws + 102400;         // N_NODES*64
    float* hB   = hA + (size_t)N_NODES * 64;

    const int nBlkNode   = (N_NODES + 255) / 256;       // 391
    const int nBlkEdge   = (N_EDGES + 255) / 256;       // 6250
    const int nBlkFeat4  = N_NODES * 16 / 256;          // 6250
    const int nBlkGemm   = N_NODES / 16;                // 6250
    const int nBlkScat   = (int)((long long)N_EDGES * 64 / 256);  // 400000

    // degree -> dinv
    k_init_deg<<<nBlkNode, 256, 0, stream>>>(dinv);
    k_count_deg<<<nBlkEdge, 256, 0, stream>>>(dst, dinv);
    k_dinv<<<nBlkNode, 256, 0, stream>>>(dinv);

    // layer 1
    k_gemm<128><<<nBlkGemm, 256, 0, stream>>>(x, W1, hA);
    k_init_agg<<<nBlkFeat4, 256, 0, stream>>>(hA, dinv, b1, out);   // d_out as agg1
    k_scatter<<<nBlkScat, 256, 0, stream>>>(hA, src, dst, dinv, out);
    k_gelu<<<nBlkFeat4, 256, 0, stream>>>(out, hA);                 // hA := gelu(agg1)

    // layer 2
    k_gemm<64><<<nBlkGemm, 256, 0, stream>>>(hA, W2, hB);
    k_init_agg<<<nBlkFeat4, 256, 0, stream>>>(hB, dinv, b2, out);
    k_scatter<<<nBlkScat, 256, 0, stream>>>(hB, src, dst, dinv, out);
}

// Round 2
// 381.639 us; speedup vs baseline: 2.3062x; 2.3062x over previous
//
#include <hip/hip_runtime.h>
#include <math.h>

#define N_NODES 100000
#define N_EDGES 1600000
#define NCHUNKS 98              // ceil(100000 / 1024)

// ---------------------------------------------------------------- zero ------
__global__ __launch_bounds__(256) void k_zero(int* counts, int* cursor) {
    int i = blockIdx.x * 256 + threadIdx.x;
    if (i < N_NODES) { counts[i] = 0; cursor[i] = 0; }
}

// ---------------------------------------------------------------- hist ------
__global__ __launch_bounds__(256) void k_hist(const int* __restrict__ dst, int* counts) {
    int e = blockIdx.x * 256 + threadIdx.x;
    if (e < N_EDGES) atomicAdd(&counts[dst[e]], 1);
}

// ---------------------------------------------------------------- dinv ------
__global__ __launch_bounds__(256) void k_dinv(const int* __restrict__ counts, float* dinv) {
    int i = blockIdx.x * 256 + threadIdx.x;
    if (i < N_NODES) dinv[i] = rsqrtf((float)(counts[i] + 1));  // +1 self-loop
}

// ----------------------------------------------------- scan (3 kernels) -----
// chunk = 1024 elements, 256 threads x 4 each
__global__ __launch_bounds__(256) void k_scan_chunk(const int* __restrict__ counts,
                                                    int* __restrict__ row_start,
                                                    int* __restrict__ chunkSums) {
    __shared__ int sd[256];
    const int t = threadIdx.x;
    const int idx0 = blockIdx.x * 1024 + t * 4;
    int v0 = (idx0 + 0 < N_NODES) ? counts[idx0 + 0] : 0;
    int v1 = (idx0 + 1 < N_NODES) ? counts[idx0 + 1] : 0;
    int v2 = (idx0 + 2 < N_NODES) ? counts[idx0 + 2] : 0;
    int v3 = (idx0 + 3 < N_NODES) ? counts[idx0 + 3] : 0;
    int s0 = v0, s1 = s0 + v1, s2 = s1 + v2, s3 = s2 + v3;
    sd[t] = s3;
    __syncthreads();
    #pragma unroll
    for (int off = 1; off < 256; off <<= 1) {
        int x = (t >= off) ? sd[t - off] : 0;
        __syncthreads();
        sd[t] += x;
        __syncthreads();
    }
    int excl = (t > 0) ? sd[t - 1] : 0;
    if (idx0 + 0 < N_NODES) row_start[idx0 + 0] = excl;
    if (idx0 + 1 < N_NODES) row_start[idx0 + 1] = excl + s0;
    if (idx0 + 2 < N_NODES) row_start[idx0 + 2] = excl + s1;
    if (idx0 + 3 < N_NODES) row_start[idx0 + 3] = excl + s2;
    if (t == 255) chunkSums[blockIdx.x] = sd[255];
}

__global__ __launch_bounds__(128) void k_scan_partials(int* chunkSums) {
    __shared__ int sd[128];
    int t = threadIdx.x;
    int v = (t < NCHUNKS) ? chunkSums[t] : 0;
    sd[t] = v;
    __syncthreads();
    #pragma unroll
    for (int off = 1; off < 128; off <<= 1) {
        int x = (t >= off) ? sd[t - off] : 0;
        __syncthreads();
        sd[t] += x;
        __syncthreads();
    }
    int excl = (t > 0) ? sd[t - 1] : 0;
    if (t < NCHUNKS) chunkSums[t] = excl;
}

__global__ __launch_bounds__(256) void k_add_offsets(int* row_start, const int* __restrict__ chunkSums) {
    int i = blockIdx.x * 256 + threadIdx.x;
    if (i < N_NODES) row_start[i] += chunkSums[i >> 10];
    if (i == 0) row_start[N_NODES] = N_EDGES;
}

// ---------------------------------------------------------------- reorder ---
__global__ __launch_bounds__(256) void k_reorder(const int* __restrict__ src,
                                                 const int* __restrict__ dst,
                                                 const int* __restrict__ row_start,
                                                 int* cursor, int* __restrict__ csr_src) {
    int e = blockIdx.x * 256 + threadIdx.x;
    if (e < N_EDGES) {
        int d = dst[e];
        int p = atomicAdd(&cursor[d], 1);
        csr_src[row_start[d] + p] = src[e];
    }
}

// ---------------------------------------------------------------- GEMM ------
// 16 rows x 64 cols per block; epilogue scales row r by dinv[r] (-> hs).
template <int FIN>
__global__ __launch_bounds__(256) void k_gemm(const float* __restrict__ X,
                                              const float* __restrict__ W,
                                              const float* __restrict__ dinv,
                                              float* __restrict__ H) {
    __shared__ float sW[FIN * 64];
    __shared__ float sx[16 * FIN];
    {
        const float4* Wv = (const float4*)W;
        float4* sWv = (float4*)sW;
        #pragma unroll
        for (int i = threadIdx.x; i < FIN * 16; i += 256) sWv[i] = Wv[i];
    }
    {
        const float4* Xv = (const float4*)(X + (size_t)blockIdx.x * 16 * FIN);
        float4* sxv = (float4*)sx;
        #pragma unroll
        for (int i = threadIdx.x; i < 4 * FIN; i += 256) sxv[i] = Xv[i];
    }
    __syncthreads();

    const int col = threadIdx.x & 63;
    const int rg  = threadIdx.x >> 6;
    float a0 = 0.f, a1 = 0.f, a2 = 0.f, a3 = 0.f;
    #pragma unroll
    for (int k = 0; k < FIN; ++k) {
        const float w = sW[k * 64 + col];
        a0 += sx[(rg * 4 + 0) * FIN + k] * w;
        a1 += sx[(rg * 4 + 1) * FIN + k] * w;
        a2 += sx[(rg * 4 + 2) * FIN + k] * w;
        a3 += sx[(rg * 4 + 3) * FIN + k] * w;
    }
    const int row0 = blockIdx.x * 16 + rg * 4;
    size_t base = (size_t)row0 * 64 + col;
    H[base +   0] = a0 * dinv[row0 + 0];
    H[base +  64] = a1 * dinv[row0 + 1];
    H[base + 128] = a2 * dinv[row0 + 2];
    H[base + 192] = a3 * dinv[row0 + 3];
}

// ---------------------------------------------------------------- aggregate -
// One 64-lane wave per node: acc = hs[self] + sum(hs[src]); out = dinv*acc + b
// (optionally GELU). 4 nodes per 256-thread block.
template <bool GELU>
__global__ __launch_bounds__(256) void k_aggregate(const float* __restrict__ hs,
                                                   const int* __restrict__ csr_src,
                                                   const int* __restrict__ row_start,
                                                   const float* __restrict__ dinv,
                                                   const float* __restrict__ b,
                                                   float* __restrict__ out) {
    const int node = blockIdx.x * 4 + (threadIdx.x >> 6);
    const int lane = threadIdx.x & 63;
    const int jEnd = row_start[node + 1];
    int j = row_start[node];
    float acc = hs[(size_t)node * 64 + lane];  // self-loop
    for (; j + 4 <= jEnd; j += 4) {
        int i0 = csr_src[j + 0];
        int i1 = csr_src[j + 1];
        int i2 = csr_src[j + 2];
        int i3 = csr_src[j + 3];
        float v0 = hs[(size_t)i0 * 64 + lane];
        float v1 = hs[(size_t)i1 * 64 + lane];
        float v2 = hs[(size_t)i2 * 64 + lane];
        float v3 = hs[(size_t)i3 * 64 + lane];
        acc += v0; acc += v1; acc += v2; acc += v3;
    }
    for (; j < jEnd; ++j) acc += hs[(size_t)csr_src[j] * 64 + lane];
    float r = dinv[node] * acc + b[lane];
    if (GELU) r = 0.5f * r * (1.0f + erff(r * 0.70710678118654752f));
    out[(size_t)node * 64 + lane] = r;
}

// ---------------------------------------------------------------- launch ----
extern "C" void kernel_launch(void* const* d_in, const int* in_sizes, int n_in,
                              void* d_out, int out_size, void* d_ws, size_t ws_size,
                              hipStream_t stream) {
    const float* x  = (const float*)d_in[0];
    const int* edge = (const int*)d_in[1];           // [2, N_EDGES] int32
    const float* W1 = (const float*)d_in[2];
    const float* b1 = (const float*)d_in[3];
    const float* W2 = (const float*)d_in[4];
    const float* b2 = (const float*)d_in[5];
    float* out = (float*)d_out;                      // [N_NODES, 64]

    const int* src = edge;
    const int* dst = edge + N_EDGES;

    char* ws = (char*)d_ws;
    int*   counts    = (int*)(ws);                         // N
    int*   cursor    = (int*)(ws + 400000);                // N
    int*   row_start = (int*)(ws + 800000);                // N+1
    int*   chunkSums = (int*)(ws + 1200004);               // 128
    float* dinv      = (float*)(ws + 1200640);             // N
    int*   csr_src   = (int*)(ws + 1600640);               // E
    float* bufA      = (float*)(ws + 8000640);             // N*64

    const int nBlkNode = (N_NODES + 255) / 256;            // 391
    const int nBlkEdge = (N_EDGES + 255) / 256;            // 6250
    const int nBlkGemm = N_NODES / 16;                     // 6250
    const int nBlkAgg  = N_NODES / 4;                      // 25000

    // ---- CSR build (once) ----
    k_zero<<<nBlkNode, 256, 0, stream>>>(counts, cursor);
    k_hist<<<nBlkEdge, 256, 0, stream>>>(dst, counts);
    k_dinv<<<nBlkNode, 256, 0, stream>>>(counts, dinv);
    k_scan_chunk<<<NCHUNKS, 256, 0, stream>>>(counts, row_start, chunkSums);
    k_scan_partials<<<1, 128, 0, stream>>>(chunkSums);
    k_add_offsets<<<nBlkNode, 256, 0, stream>>>(row_start, chunkSums);
    k_reorder<<<nBlkEdge, 256, 0, stream>>>(src, dst, row_start, cursor, csr_src);

    // ---- layer 1 ----
    k_gemm<128><<<nBlkGemm, 256, 0, stream>>>(x, W1, dinv, bufA);       // hs1
    k_aggregate<true><<<nBlkAgg, 256, 0, stream>>>(bufA, csr_src, row_start, dinv, b1, out);  // out1 = gelu(...)

    // ---- layer 2 ----
    k_gemm<64><<<nBlkGemm, 256, 0, stream>>>(out, W2, dinv, bufA);      // hs2
    k_aggregate<false><<<nBlkAgg, 256, 0, stream>>>(bufA, csr_src, row_start, dinv, b2, out);
}

// Round 3
// 252.197 us; speedup vs baseline: 3.4899x; 1.5133x over previous
//
#include <hip/hip_runtime.h>
#include <math.h>

#define N_NODES 100000
#define N_EDGES 1600000
#define NBUK 196          // dst>>9 -> 0..195 (512 nodes per bucket)
#define BCAP 16000        // entries per bucket region (mean 8192, sd ~90)
#define BINCHUNK 4096     // edges per k_bin block (256 thr x 16)

// ------------------------------------------------------------ zero cursors --
__global__ __launch_bounds__(256) void k_zero196(int* bucketCursor) {
    if (threadIdx.x < NBUK) bucketCursor[threadIdx.x] = 0;
}

// ---------------------------------------------------------------- binning ---
// Block-local LDS histogram over 196 coarse buckets; one global atomic per
// (block,bucket) to reserve; packed 4B entries appended in contiguous runs.
__global__ __launch_bounds__(256) void k_bin(const int* __restrict__ src,
                                             const int* __restrict__ dst,
                                             int* bucketCursor,
                                             unsigned int* __restrict__ bins) {
    __shared__ int lcnt[NBUK];
    __shared__ int lbase[NBUK];
    const int t = threadIdx.x;
    if (t < NBUK) lcnt[t] = 0;
    __syncthreads();

    const int e0 = blockIdx.x * BINCHUNK + t * 16;
    int4 s4[4], d4[4];
    int bkt[16], rnk[16];
    const bool valid = e0 < N_EDGES;   // N_EDGES % 16 == 0 -> all-or-nothing
    if (valid) {
        #pragma unroll
        for (int k = 0; k < 4; ++k) {
            s4[k] = *(const int4*)(src + e0 + 4 * k);
            d4[k] = *(const int4*)(dst + e0 + 4 * k);
        }
        #pragma unroll
        for (int k = 0; k < 4; ++k) {
            int dd[4] = { d4[k].x, d4[k].y, d4[k].z, d4[k].w };
            #pragma unroll
            for (int j = 0; j < 4; ++j) {
                int b = dd[j] >> 9;
                bkt[4 * k + j] = b;
                rnk[4 * k + j] = atomicAdd(&lcnt[b], 1);
            }
        }
    }
    __syncthreads();
    if (t < NBUK && lcnt[t] > 0) lbase[t] = atomicAdd(&bucketCursor[t], lcnt[t]);
    __syncthreads();
    if (valid) {
        #pragma unroll
        for (int k = 0; k < 4; ++k) {
            int ss[4] = { s4[k].x, s4[k].y, s4[k].z, s4[k].w };
            int dd[4] = { d4[k].x, d4[k].y, d4[k].z, d4[k].w };
            #pragma unroll
            for (int j = 0; j < 4; ++j) {
                int i = 4 * k + j;
                unsigned w = ((unsigned)(dd[j] & 511) << 17) | (unsigned)ss[j];
                bins[(size_t)bkt[i] * BCAP + lbase[bkt[i]] + rnk[i]] = w;
            }
        }
    }
}

// ------------------------------------------------- bucket-total scan (1 wg) -
__global__ __launch_bounds__(256) void k_bscan(const int* __restrict__ bucketCursor,
                                               int* __restrict__ gBase,
                                               int* __restrict__ row_start) {
    __shared__ int sd[256];
    const int t = threadIdx.x;
    int v = (t < NBUK) ? bucketCursor[t] : 0;
    sd[t] = v;
    __syncthreads();
    #pragma unroll
    for (int off = 1; off < 256; off <<= 1) {
        int x = (t >= off) ? sd[t - off] : 0;
        __syncthreads();
        sd[t] += x;
        __syncthreads();
    }
    if (t < NBUK) gBase[t] = (t > 0) ? sd[t - 1] : 0;
    if (t == 0) row_start[N_NODES] = N_EDGES;
}

// ------------------------------------------- per-bucket CSR build (no glob) -
// One block per bucket: LDS histogram of 512 nodes, local scan, write
// row_start/dinv sequentially, scatter csr_src into own L2-local window.
__global__ __launch_bounds__(256) void k_build(const unsigned int* __restrict__ bins,
                                               const int* __restrict__ bucketCursor,
                                               const int* __restrict__ gBase,
                                               int* __restrict__ row_start,
                                               float* __restrict__ dinv,
                                               int* __restrict__ csr_src) {
    __shared__ int cnt[512];
    __shared__ int psum[256];
    __shared__ int cur[512];
    const int b = blockIdx.x;
    const int t = threadIdx.x;
    const int bcnt = bucketCursor[b];
    const int gb = gBase[b];
    const unsigned int* mybins = bins + (size_t)b * BCAP;

    cnt[t] = 0; cnt[t + 256] = 0;
    __syncthreads();
    for (int i = t; i < bcnt; i += 256) {
        unsigned w = mybins[i];
        atomicAdd(&cnt[w >> 17], 1);
    }
    __syncthreads();
    // scan 512 via 256 pair-sums
    int c0 = cnt[2 * t], c1 = cnt[2 * t + 1];
    psum[t] = c0 + c1;
    __syncthreads();
    #pragma unroll
    for (int off = 1; off < 256; off <<= 1) {
        int x = (t >= off) ? psum[t - off] : 0;
        __syncthreads();
        psum[t] += x;
        __syncthreads();
    }
    int exclPair = (t > 0) ? psum[t - 1] : 0;
    int o0 = exclPair, o1 = exclPair + c0;
    cur[2 * t] = o0; cur[2 * t + 1] = o1;
    const int nb = b << 9;
    if (nb + 2 * t < N_NODES) {
        row_start[nb + 2 * t] = gb + o0;
        dinv[nb + 2 * t] = rsqrtf((float)(c0 + 1));
    }
    if (nb + 2 * t + 1 < N_NODES) {
        row_start[nb + 2 * t + 1] = gb + o1;
        dinv[nb + 2 * t + 1] = rsqrtf((float)(c1 + 1));
    }
    __syncthreads();
    for (int i = t; i < bcnt; i += 256) {
        unsigned w = mybins[i];
        int dl = w >> 17;
        int s = (int)(w & 0x1FFFFu);
        int p = atomicAdd(&cur[dl], 1);
        csr_src[gb + p] = s;
    }
}

// ---------------------------------------------------------------- GEMM ------
// 16 rows x 64 cols per block; epilogue scales row r by dinv[r] (-> hs).
template <int FIN>
__global__ __launch_bounds__(256) void k_gemm(const float* __restrict__ X,
                                              const float* __restrict__ W,
                                              const float* __restrict__ dinv,
                                              float* __restrict__ H) {
    __shared__ float sW[FIN * 64];
    __shared__ float sx[16 * FIN];
    {
        const float4* Wv = (const float4*)W;
        float4* sWv = (float4*)sW;
        #pragma unroll
        for (int i = threadIdx.x; i < FIN * 16; i += 256) sWv[i] = Wv[i];
    }
    {
        const float4* Xv = (const float4*)(X + (size_t)blockIdx.x * 16 * FIN);
        float4* sxv = (float4*)sx;
        #pragma unroll
        for (int i = threadIdx.x; i < 4 * FIN; i += 256) sxv[i] = Xv[i];
    }
    __syncthreads();

    const int col = threadIdx.x & 63;
    const int rg  = threadIdx.x >> 6;
    float a0 = 0.f, a1 = 0.f, a2 = 0.f, a3 = 0.f;
    #pragma unroll
    for (int k = 0; k < FIN; ++k) {
        const float w = sW[k * 64 + col];
        a0 += sx[(rg * 4 + 0) * FIN + k] * w;
        a1 += sx[(rg * 4 + 1) * FIN + k] * w;
        a2 += sx[(rg * 4 + 2) * FIN + k] * w;
        a3 += sx[(rg * 4 + 3) * FIN + k] * w;
    }
    const int row0 = blockIdx.x * 16 + rg * 4;
    size_t base = (size_t)row0 * 64 + col;
    H[base +   0] = a0 * dinv[row0 + 0];
    H[base +  64] = a1 * dinv[row0 + 1];
    H[base + 128] = a2 * dinv[row0 + 2];
    H[base + 192] = a3 * dinv[row0 + 3];
}

// ---------------------------------------------------------------- aggregate -
// One wave per node; 4 quarters of 16 lanes each gather a full 64-float row
// as float4 (16 B/lane). Cross-quarter reduce via __shfl_xor(16|32).
template <bool GELU>
__global__ __launch_bounds__(256) void k_aggregate(const float* __restrict__ hs,
                                                   const int* __restrict__ csr_src,
                                                   const int* __restrict__ row_start,
                                                   const float* __restrict__ dinv,
                                                   const float* __restrict__ b,
                                                   float* __restrict__ out) {
    const int node = blockIdx.x * 4 + (threadIdx.x >> 6);
    const int lane = threadIdx.x & 63;
    const int q    = lane >> 4;      // quarter 0..3
    const int lj   = lane & 15;      // float4 index within row
    const float4* hs4 = (const float4*)hs;   // row stride = 16 float4

    const int jS = row_start[node];
    const int jE = row_start[node + 1];
    float4 acc = make_float4(0.f, 0.f, 0.f, 0.f);
    if (q == 0) acc = hs4[(size_t)node * 16 + lj];        // self-loop
    for (int j = jS + q; j < jE; j += 4) {
        int r = csr_src[j];
        float4 v = hs4[(size_t)r * 16 + lj];
        acc.x += v.x; acc.y += v.y; acc.z += v.z; acc.w += v.w;
    }
    // reduce across the 4 quarters (lanes lj, lj+16, lj+32, lj+48)
    acc.x += __shfl_xor(acc.x, 16); acc.y += __shfl_xor(acc.y, 16);
    acc.z += __shfl_xor(acc.z, 16); acc.w += __shfl_xor(acc.w, 16);
    acc.x += __shfl_xor(acc.x, 32); acc.y += __shfl_xor(acc.y, 32);
    acc.z += __shfl_xor(acc.z, 32); acc.w += __shfl_xor(acc.w, 32);

    const float di = dinv[node];
    float4 bb = ((const float4*)b)[lj];
    float4 r;
    r.x = di * acc.x + bb.x;
    r.y = di * acc.y + bb.y;
    r.z = di * acc.z + bb.z;
    r.w = di * acc.w + bb.w;
    if (GELU) {
        r.x = 0.5f * r.x * (1.0f + erff(r.x * 0.70710678118654752f));
        r.y = 0.5f * r.y * (1.0f + erff(r.y * 0.70710678118654752f));
        r.z = 0.5f * r.z * (1.0f + erff(r.z * 0.70710678118654752f));
        r.w = 0.5f * r.w * (1.0f + erff(r.w * 0.70710678118654752f));
    }
    if (q == 0) ((float4*)out)[(size_t)node * 16 + lj] = r;
}

// ---------------------------------------------------------------- launch ----
extern "C" void kernel_launch(void* const* d_in, const int* in_sizes, int n_in,
                              void* d_out, int out_size, void* d_ws, size_t ws_size,
                              hipStream_t stream) {
    const float* x  = (const float*)d_in[0];
    const int* edge = (const int*)d_in[1];           // [2, N_EDGES] int32
    const float* W1 = (const float*)d_in[2];
    const float* b1 = (const float*)d_in[3];
    const float* W2 = (const float*)d_in[4];
    const float* b2 = (const float*)d_in[5];
    float* out = (float*)d_out;                      // [N_NODES, 64]

    const int* src = edge;
    const int* dst = edge + N_EDGES;

    char* ws = (char*)d_ws;
    int*   bucketCursor = (int*)(ws);                 // 196 -> 1KB
    int*   gBase        = (int*)(ws + 1024);          // 196 -> 1KB
    int*   row_start    = (int*)(ws + 2048);          // N+1
    float* dinv         = (float*)(ws + 402176);      // N
    int*   csr_src      = (int*)(ws + 802304);        // E
    float* bufA         = (float*)(ws + 7202304);     // N*64 floats (25.6MB)
    unsigned int* bins  = (unsigned int*)bufA;        // 196*16000*4 = 12.5MB, dead before gemm1

    const int nBlkBin  = (N_EDGES + BINCHUNK - 1) / BINCHUNK;  // 391
    const int nBlkGemm = N_NODES / 16;                         // 6250
    const int nBlkAgg  = N_NODES / 4;                          // 25000

    // ---- CSR build ----
    k_zero196<<<1, 256, 0, stream>>>(bucketCursor);
    k_bin<<<nBlkBin, 256, 0, stream>>>(src, dst, bucketCursor, bins);
    k_bscan<<<1, 256, 0, stream>>>(bucketCursor, gBase, row_start);
    k_build<<<NBUK, 256, 0, stream>>>(bins, bucketCursor, gBase, row_start, dinv, csr_src);

    // ---- layer 1 ----
    k_gemm<128><<<nBlkGemm, 256, 0, stream>>>(x, W1, dinv, bufA);
    k_aggregate<true><<<nBlkAgg, 256, 0, stream>>>(bufA, csr_src, row_start, dinv, b1, out);

    // ---- layer 2 ----
    k_gemm<64><<<nBlkGemm, 256, 0, stream>>>(out, W2, dinv, bufA);
    k_aggregate<false><<<nBlkAgg, 256, 0, stream>>>(bufA, csr_src, row_start, dinv, b2, out);
}

// Round 4
// 217.804 us; speedup vs baseline: 4.0410x; 1.1579x over previous
//
#include <hip/hip_runtime.h>
#include <math.h>

#define N_NODES 100000
#define N_EDGES 1600000
#define NBUK 196          // dst>>9 -> 0..195 (512 nodes per bucket)
#define BCAP 16000        // entries per bucket region (mean 8192)
#define BINCHUNK 4096     // edges per k_bin block (256 thr x 16)

typedef unsigned short u16;
typedef u16 u16x8 __attribute__((ext_vector_type(8)));

__device__ __forceinline__ float bf2f(u16 u) {
    union { unsigned i; float f; } v; v.i = ((unsigned)u) << 16; return v.f;
}
__device__ __forceinline__ u16 f2bf(float f) {
    union { float f; unsigned i; } v; v.f = f;
    return (u16)((v.i + 0x7FFFu + ((v.i >> 16) & 1u)) >> 16);  // RNE
}

// ---------------------------------------------------------------- binning ---
__global__ __launch_bounds__(256) void k_bin(const int* __restrict__ src,
                                             const int* __restrict__ dst,
                                             int* bucketCursor,
                                             unsigned int* __restrict__ bins) {
    __shared__ int lcnt[NBUK];
    __shared__ int lbase[NBUK];
    const int t = threadIdx.x;
    if (t < NBUK) lcnt[t] = 0;
    __syncthreads();

    const int e0 = blockIdx.x * BINCHUNK + t * 16;
    int4 s4[4], d4[4];
    int bkt[16], rnk[16];
    const bool valid = e0 < N_EDGES;   // N_EDGES % 16 == 0
    if (valid) {
        #pragma unroll
        for (int k = 0; k < 4; ++k) {
            s4[k] = *(const int4*)(src + e0 + 4 * k);
            d4[k] = *(const int4*)(dst + e0 + 4 * k);
        }
        #pragma unroll
        for (int k = 0; k < 4; ++k) {
            int dd[4] = { d4[k].x, d4[k].y, d4[k].z, d4[k].w };
            #pragma unroll
            for (int j = 0; j < 4; ++j) {
                int b = dd[j] >> 9;
                bkt[4 * k + j] = b;
                rnk[4 * k + j] = atomicAdd(&lcnt[b], 1);
            }
        }
    }
    __syncthreads();
    if (t < NBUK && lcnt[t] > 0) lbase[t] = atomicAdd(&bucketCursor[t], lcnt[t]);
    __syncthreads();
    if (valid) {
        #pragma unroll
        for (int k = 0; k < 4; ++k) {
            int ss[4] = { s4[k].x, s4[k].y, s4[k].z, s4[k].w };
            int dd[4] = { d4[k].x, d4[k].y, d4[k].z, d4[k].w };
            #pragma unroll
            for (int j = 0; j < 4; ++j) {
                int i = 4 * k + j;
                unsigned w = ((unsigned)(dd[j] & 511) << 17) | (unsigned)ss[j];
                bins[(size_t)bkt[i] * BCAP + lbase[bkt[i]] + rnk[i]] = w;
            }
        }
    }
}

// ------------------------------------------------- bucket-total scan (1 wg) -
__global__ __launch_bounds__(256) void k_bscan(const int* __restrict__ bucketCursor,
                                               int* __restrict__ gBase,
                                               int* __restrict__ row_start) {
    __shared__ int sd[256];
    const int t = threadIdx.x;
    int v = (t < NBUK) ? bucketCursor[t] : 0;
    sd[t] = v;
    __syncthreads();
    #pragma unroll
    for (int off = 1; off < 256; off <<= 1) {
        int x = (t >= off) ? sd[t - off] : 0;
        __syncthreads();
        sd[t] += x;
        __syncthreads();
    }
    if (t < NBUK) gBase[t] = (t > 0) ? sd[t - 1] : 0;
    if (t == 0) row_start[N_NODES] = N_EDGES;
}

// ------------------------------------------- per-bucket CSR build -----------
__global__ __launch_bounds__(256) void k_build(const unsigned int* __restrict__ bins,
                                               const int* __restrict__ bucketCursor,
                                               const int* __restrict__ gBase,
                                               int* __restrict__ row_start,
                                               float* __restrict__ dinv,
                                               int* __restrict__ csr_src) {
    __shared__ int cnt[512];
    __shared__ int psum[256];
    __shared__ int cur[512];
    const int b = blockIdx.x;
    const int t = threadIdx.x;
    const int bcnt = bucketCursor[b];
    const int gb = gBase[b];
    const unsigned int* mybins = bins + (size_t)b * BCAP;

    cnt[t] = 0; cnt[t + 256] = 0;
    __syncthreads();
    for (int i = t; i < bcnt; i += 256) {
        unsigned w = mybins[i];
        atomicAdd(&cnt[w >> 17], 1);
    }
    __syncthreads();
    int c0 = cnt[2 * t], c1 = cnt[2 * t + 1];
    psum[t] = c0 + c1;
    __syncthreads();
    #pragma unroll
    for (int off = 1; off < 256; off <<= 1) {
        int x = (t >= off) ? psum[t - off] : 0;
        __syncthreads();
        psum[t] += x;
        __syncthreads();
    }
    int exclPair = (t > 0) ? psum[t - 1] : 0;
    int o0 = exclPair, o1 = exclPair + c0;
    cur[2 * t] = o0; cur[2 * t + 1] = o1;
    const int nb = b << 9;
    if (nb + 2 * t < N_NODES) {
        row_start[nb + 2 * t] = gb + o0;
        dinv[nb + 2 * t] = rsqrtf((float)(c0 + 1));
    }
    if (nb + 2 * t + 1 < N_NODES) {
        row_start[nb + 2 * t + 1] = gb + o1;
        dinv[nb + 2 * t + 1] = rsqrtf((float)(c1 + 1));
    }
    __syncthreads();
    for (int i = t; i < bcnt; i += 256) {
        unsigned w = mybins[i];
        int dl = w >> 17;
        int s = (int)(w & 0x1FFFFu);
        int p = atomicAdd(&cur[dl], 1);
        csr_src[gb + p] = s;
    }
}

// ---------------------------------------------------------------- GEMM ------
// 16 rows x 64 cols per block; epilogue scales row r by dinv[r] and emits bf16.
// BF16IN: input rows are bf16 (64 cols); else fp32 (FIN cols).
template <int FIN, bool BF16IN>
__global__ __launch_bounds__(256) void k_gemm(const void* __restrict__ Xraw,
                                              const float* __restrict__ W,
                                              const float* __restrict__ dinv,
                                              u16* __restrict__ H) {
    __shared__ float sW[FIN * 64];
    __shared__ float sx[16 * FIN];
    {
        const float4* Wv = (const float4*)W;
        float4* sWv = (float4*)sW;
        #pragma unroll
        for (int i = threadIdx.x; i < FIN * 16; i += 256) sWv[i] = Wv[i];
    }
    if constexpr (BF16IN) {
        const u16x8* Xv = (const u16x8*)((const u16*)Xraw + (size_t)blockIdx.x * 16 * FIN);
        for (int i = threadIdx.x; i < 2 * FIN; i += 256) {  // 16*FIN/8 vectors
            u16x8 v = Xv[i];
            float* dp = &sx[i * 8];
            #pragma unroll
            for (int k = 0; k < 8; ++k) dp[k] = bf2f(v[k]);
        }
    } else {
        const float4* Xv = (const float4*)((const float*)Xraw + (size_t)blockIdx.x * 16 * FIN);
        #pragma unroll
        for (int i = threadIdx.x; i < 4 * FIN; i += 256) ((float4*)sx)[i] = Xv[i];
    }
    __syncthreads();

    const int col = threadIdx.x & 63;
    const int rg  = threadIdx.x >> 6;
    float a0 = 0.f, a1 = 0.f, a2 = 0.f, a3 = 0.f;
    #pragma unroll
    for (int k = 0; k < FIN; ++k) {
        const float w = sW[k * 64 + col];
        a0 += sx[(rg * 4 + 0) * FIN + k] * w;
        a1 += sx[(rg * 4 + 1) * FIN + k] * w;
        a2 += sx[(rg * 4 + 2) * FIN + k] * w;
        a3 += sx[(rg * 4 + 3) * FIN + k] * w;
    }
    const int row0 = blockIdx.x * 16 + rg * 4;
    size_t base = (size_t)row0 * 64 + col;
    H[base +   0] = f2bf(a0 * dinv[row0 + 0]);
    H[base +  64] = f2bf(a1 * dinv[row0 + 1]);
    H[base + 128] = f2bf(a2 * dinv[row0 + 2]);
    H[base + 192] = f2bf(a3 * dinv[row0 + 3]);
}

// ---------------------------------------------------------------- aggregate -
// One wave per node; 8 groups of 8 lanes; each lane gathers ushort8 (16B) of a
// row, fp32 accumulate, __shfl_xor(8/16/32) cross-group reduce.
// GELU=true -> bf16 output (layer-1), else fp32 output (final).
template <bool GELU>
__global__ __launch_bounds__(256) void k_aggregate(const u16* __restrict__ hs,
                                                   const int* __restrict__ csr_src,
                                                   const int* __restrict__ row_start,
                                                   const float* __restrict__ dinv,
                                                   const float* __restrict__ b,
                                                   void* __restrict__ outraw) {
    const int node = blockIdx.x * 4 + (threadIdx.x >> 6);
    const int lane = threadIdx.x & 63;
    const int g    = lane >> 3;      // edge-parallel group 0..7
    const int lj   = lane & 7;       // ushort8 index within row
    const u16x8* hs8 = (const u16x8*)hs;   // row stride = 8 vectors

    const int jS = row_start[node];
    const int jE = row_start[node + 1];
    float acc[8] = {0.f, 0.f, 0.f, 0.f, 0.f, 0.f, 0.f, 0.f};
    if (g == 0) {  // self-loop
        u16x8 v = hs8[(size_t)node * 8 + lj];
        #pragma unroll
        for (int k = 0; k < 8; ++k) acc[k] = bf2f(v[k]);
    }
    for (int j = jS + g; j < jE; j += 8) {
        int r = csr_src[j];
        u16x8 v = hs8[(size_t)r * 8 + lj];
        #pragma unroll
        for (int k = 0; k < 8; ++k) acc[k] += bf2f(v[k]);
    }
    #pragma unroll
    for (int m = 8; m <= 32; m <<= 1) {
        #pragma unroll
        for (int k = 0; k < 8; ++k) acc[k] += __shfl_xor(acc[k], m);
    }
    if (g == 0) {
        const float di = dinv[node];
        float4 bb0 = ((const float4*)b)[lj * 2];
        float4 bb1 = ((const float4*)b)[lj * 2 + 1];
        float r[8];
        r[0] = di * acc[0] + bb0.x; r[1] = di * acc[1] + bb0.y;
        r[2] = di * acc[2] + bb0.z; r[3] = di * acc[3] + bb0.w;
        r[4] = di * acc[4] + bb1.x; r[5] = di * acc[5] + bb1.y;
        r[6] = di * acc[6] + bb1.z; r[7] = di * acc[7] + bb1.w;
        if (GELU) {
            #pragma unroll
            for (int k = 0; k < 8; ++k)
                r[k] = 0.5f * r[k] * (1.0f + erff(r[k] * 0.70710678118654752f));
            u16x8 o;
            #pragma unroll
            for (int k = 0; k < 8; ++k) o[k] = f2bf(r[k]);
            ((u16x8*)outraw)[(size_t)node * 8 + lj] = o;
        } else {
            float4 o0 = make_float4(r[0], r[1], r[2], r[3]);
            float4 o1 = make_float4(r[4], r[5], r[6], r[7]);
            ((float4*)outraw)[(size_t)node * 16 + lj * 2] = o0;
            ((float4*)outraw)[(size_t)node * 16 + lj * 2 + 1] = o1;
        }
    }
}

// ---------------------------------------------------------------- launch ----
extern "C" void kernel_launch(void* const* d_in, const int* in_sizes, int n_in,
                              void* d_out, int out_size, void* d_ws, size_t ws_size,
                              hipStream_t stream) {
    const float* x  = (const float*)d_in[0];
    const int* edge = (const int*)d_in[1];           // [2, N_EDGES] int32
    const float* W1 = (const float*)d_in[2];
    const float* b1 = (const float*)d_in[3];
    const float* W2 = (const float*)d_in[4];
    const float* b2 = (const float*)d_in[5];
    float* out = (float*)d_out;                      // [N_NODES, 64] fp32

    const int* src = edge;
    const int* dst = edge + N_EDGES;

    char* ws = (char*)d_ws;
    int*   bucketCursor = (int*)(ws);                 // 196
    int*   gBase        = (int*)(ws + 1024);          // 196
    int*   row_start    = (int*)(ws + 2048);          // N+1
    float* dinv         = (float*)(ws + 402176);      // N
    int*   csr_src      = (int*)(ws + 802304);        // E  (ends 7202304)
    u16*   hsb          = (u16*)(ws + 7202304);       // N*64 bf16 = 12.8MB (ends 20002304)
    unsigned int* bins  = (unsigned int*)hsb;         // 196*16000*4 = 12.54MB, dead before gemm1
    u16*   out1b        = (u16*)(ws + 20002304);      // N*64 bf16 (ends 32802304)

    const int nBlkBin  = (N_EDGES + BINCHUNK - 1) / BINCHUNK;  // 391
    const int nBlkGemm = N_NODES / 16;                         // 6250
    const int nBlkAgg  = N_NODES / 4;                          // 25000

    // ---- CSR build ----
    hipMemsetAsync(bucketCursor, 0, NBUK * sizeof(int), stream);
    k_bin<<<nBlkBin, 256, 0, stream>>>(src, dst, bucketCursor, bins);
    k_bscan<<<1, 256, 0, stream>>>(bucketCursor, gBase, row_start);
    k_build<<<NBUK, 256, 0, stream>>>(bins, bucketCursor, gBase, row_start, dinv, csr_src);

    // ---- layer 1 ----
    k_gemm<128, false><<<nBlkGemm, 256, 0, stream>>>(x, W1, dinv, hsb);
    k_aggregate<true><<<nBlkAgg, 256, 0, stream>>>(hsb, csr_src, row_start, dinv, b1, out1b);

    // ---- layer 2 ----
    k_gemm<64, true><<<nBlkGemm, 256, 0, stream>>>(out1b, W2, dinv, hsb);
    k_aggregate<false><<<nBlkAgg, 256, 0, stream>>>(hsb, csr_src, row_start, dinv, b2, out);
}

// Round 5
// 217.329 us; speedup vs baseline: 4.0498x; 1.0022x over previous
//
#include <hip/hip_runtime.h>
#include <math.h>

#define N_NODES 100000
#define N_EDGES 1600000
#define NBUK 196          // dst>>9 -> 0..195 (512 nodes per bucket)
#define BCAP 16000        // entries per bucket region (mean 8192)
#define BINCHUNK 4096     // edges per k_bin block (256 thr x 16)

typedef unsigned short u16;
typedef u16 u16x8 __attribute__((ext_vector_type(8)));

__device__ __forceinline__ float bf2f(u16 u) {
    union { unsigned i; float f; } v; v.i = ((unsigned)u) << 16; return v.f;
}
__device__ __forceinline__ u16 f2bf(float f) {
    union { float f; unsigned i; } v; v.f = f;
    return (u16)((v.i + 0x7FFFu + ((v.i >> 16) & 1u)) >> 16);  // RNE
}

// ---------------------------------------------------------------- binning ---
__global__ __launch_bounds__(256) void k_bin(const int* __restrict__ src,
                                             const int* __restrict__ dst,
                                             int* bucketCursor,
                                             unsigned int* __restrict__ bins) {
    __shared__ int lcnt[NBUK];
    __shared__ int lbase[NBUK];
    const int t = threadIdx.x;
    if (t < NBUK) lcnt[t] = 0;
    __syncthreads();

    const int e0 = blockIdx.x * BINCHUNK + t * 16;
    int4 s4[4], d4[4];
    int bkt[16], rnk[16];
    const bool valid = e0 < N_EDGES;   // N_EDGES % 16 == 0
    if (valid) {
        #pragma unroll
        for (int k = 0; k < 4; ++k) {
            s4[k] = *(const int4*)(src + e0 + 4 * k);
            d4[k] = *(const int4*)(dst + e0 + 4 * k);
        }
        #pragma unroll
        for (int k = 0; k < 4; ++k) {
            int dd[4] = { d4[k].x, d4[k].y, d4[k].z, d4[k].w };
            #pragma unroll
            for (int j = 0; j < 4; ++j) {
                int b = dd[j] >> 9;
                bkt[4 * k + j] = b;
                rnk[4 * k + j] = atomicAdd(&lcnt[b], 1);
            }
        }
    }
    __syncthreads();
    if (t < NBUK && lcnt[t] > 0) lbase[t] = atomicAdd(&bucketCursor[t], lcnt[t]);
    __syncthreads();
    if (valid) {
        #pragma unroll
        for (int k = 0; k < 4; ++k) {
            int ss[4] = { s4[k].x, s4[k].y, s4[k].z, s4[k].w };
            int dd[4] = { d4[k].x, d4[k].y, d4[k].z, d4[k].w };
            #pragma unroll
            for (int j = 0; j < 4; ++j) {
                int i = 4 * k + j;
                unsigned w = ((unsigned)(dd[j] & 511) << 17) | (unsigned)ss[j];
                bins[(size_t)bkt[i] * BCAP + lbase[bkt[i]] + rnk[i]] = w;
            }
        }
    }
}

// ------------------------------------------------- bucket-total scan (1 wg) -
__global__ __launch_bounds__(256) void k_bscan(const int* __restrict__ bucketCursor,
                                               int* __restrict__ gBase,
                                               int* __restrict__ row_start) {
    __shared__ int sd[256];
    const int t = threadIdx.x;
    int v = (t < NBUK) ? bucketCursor[t] : 0;
    sd[t] = v;
    __syncthreads();
    #pragma unroll
    for (int off = 1; off < 256; off <<= 1) {
        int x = (t >= off) ? sd[t - off] : 0;
        __syncthreads();
        sd[t] += x;
        __syncthreads();
    }
    if (t < NBUK) gBase[t] = (t > 0) ? sd[t - 1] : 0;
    if (t == 0) row_start[N_NODES] = N_EDGES;
}

// ------------------------------------------- per-bucket CSR build -----------
__global__ __launch_bounds__(256) void k_build(const unsigned int* __restrict__ bins,
                                               const int* __restrict__ bucketCursor,
                                               const int* __restrict__ gBase,
                                               int* __restrict__ row_start,
                                               float* __restrict__ dinv,
                                               int* __restrict__ csr_src) {
    __shared__ int cnt[512];
    __shared__ int psum[256];
    __shared__ int cur[512];
    const int b = blockIdx.x;
    const int t = threadIdx.x;
    const int bcnt = bucketCursor[b];
    const int gb = gBase[b];
    const unsigned int* mybins = bins + (size_t)b * BCAP;

    cnt[t] = 0; cnt[t + 256] = 0;
    __syncthreads();
    for (int i = t; i < bcnt; i += 256) {
        unsigned w = mybins[i];
        atomicAdd(&cnt[w >> 17], 1);
    }
    __syncthreads();
    int c0 = cnt[2 * t], c1 = cnt[2 * t + 1];
    psum[t] = c0 + c1;
    __syncthreads();
    #pragma unroll
    for (int off = 1; off < 256; off <<= 1) {
        int x = (t >= off) ? psum[t - off] : 0;
        __syncthreads();
        psum[t] += x;
        __syncthreads();
    }
    int exclPair = (t > 0) ? psum[t - 1] : 0;
    int o0 = exclPair, o1 = exclPair + c0;
    cur[2 * t] = o0; cur[2 * t + 1] = o1;
    const int nb = b << 9;
    if (nb + 2 * t < N_NODES) {
        row_start[nb + 2 * t] = gb + o0;
        dinv[nb + 2 * t] = rsqrtf((float)(c0 + 1));
    }
    if (nb + 2 * t + 1 < N_NODES) {
        row_start[nb + 2 * t + 1] = gb + o1;
        dinv[nb + 2 * t + 1] = rsqrtf((float)(c1 + 1));
    }
    __syncthreads();
    for (int i = t; i < bcnt; i += 256) {
        unsigned w = mybins[i];
        int dl = w >> 17;
        int s = (int)(w & 0x1FFFFu);
        int p = atomicAdd(&cur[dl], 1);
        csr_src[gb + p] = s;
    }
}

// ---------------------------------------------------------------- GEMM ------
// 16 rows x 64 cols per block; epilogue scales row r by dinv[r] and emits bf16.
template <int FIN, bool BF16IN>
__global__ __launch_bounds__(256) void k_gemm(const void* __restrict__ Xraw,
                                              const float* __restrict__ W,
                                              const float* __restrict__ dinv,
                                              u16* __restrict__ H) {
    __shared__ float sW[FIN * 64];
    __shared__ float sx[16 * FIN];
    {
        const float4* Wv = (const float4*)W;
        float4* sWv = (float4*)sW;
        #pragma unroll
        for (int i = threadIdx.x; i < FIN * 16; i += 256) sWv[i] = Wv[i];
    }
    if constexpr (BF16IN) {
        const u16x8* Xv = (const u16x8*)((const u16*)Xraw + (size_t)blockIdx.x * 16 * FIN);
        for (int i = threadIdx.x; i < 2 * FIN; i += 256) {
            u16x8 v = Xv[i];
            float* dp = &sx[i * 8];
            #pragma unroll
            for (int k = 0; k < 8; ++k) dp[k] = bf2f(v[k]);
        }
    } else {
        const float4* Xv = (const float4*)((const float*)Xraw + (size_t)blockIdx.x * 16 * FIN);
        #pragma unroll
        for (int i = threadIdx.x; i < 4 * FIN; i += 256) ((float4*)sx)[i] = Xv[i];
    }
    __syncthreads();

    const int col = threadIdx.x & 63;
    const int rg  = threadIdx.x >> 6;
    float a0 = 0.f, a1 = 0.f, a2 = 0.f, a3 = 0.f;
    #pragma unroll
    for (int k = 0; k < FIN; ++k) {
        const float w = sW[k * 64 + col];
        a0 += sx[(rg * 4 + 0) * FIN + k] * w;
        a1 += sx[(rg * 4 + 1) * FIN + k] * w;
        a2 += sx[(rg * 4 + 2) * FIN + k] * w;
        a3 += sx[(rg * 4 + 3) * FIN + k] * w;
    }
    const int row0 = blockIdx.x * 16 + rg * 4;
    size_t base = (size_t)row0 * 64 + col;
    H[base +   0] = f2bf(a0 * dinv[row0 + 0]);
    H[base +  64] = f2bf(a1 * dinv[row0 + 1]);
    H[base + 128] = f2bf(a2 * dinv[row0 + 2]);
    H[base + 192] = f2bf(a3 * dinv[row0 + 3]);
}

// ---------------------------------------------------------------- aggregate -
// One wave per node; lane = feature column. Per edge: one 2B load per lane
// (128 B contiguous per wave), cvt, add. No cross-lane reduce; epilogue is
// 1 bias + 1 erf per lane. Unroll 8 for memory-level parallelism.
template <bool GELU>
__global__ __launch_bounds__(256) void k_aggregate(const u16* __restrict__ hs,
                                                   const int* __restrict__ csr_src,
                                                   const int* __restrict__ row_start,
                                                   const float* __restrict__ dinv,
                                                   const float* __restrict__ b,
                                                   void* __restrict__ outraw) {
    const int node = __builtin_amdgcn_readfirstlane(blockIdx.x * 4 + (threadIdx.x >> 6));
    const int lane = threadIdx.x & 63;
    const u16* __restrict__ col = hs + lane;

    const int jS = row_start[node];
    const int jE = row_start[node + 1];
    float acc = bf2f(col[(size_t)node << 6]);   // self-loop
    int j = jS;
    for (; j + 8 <= jE; j += 8) {
        int r0 = csr_src[j + 0], r1 = csr_src[j + 1];
        int r2 = csr_src[j + 2], r3 = csr_src[j + 3];
        int r4 = csr_src[j + 4], r5 = csr_src[j + 5];
        int r6 = csr_src[j + 6], r7 = csr_src[j + 7];
        u16 v0 = col[(size_t)r0 << 6];
        u16 v1 = col[(size_t)r1 << 6];
        u16 v2 = col[(size_t)r2 << 6];
        u16 v3 = col[(size_t)r3 << 6];
        u16 v4 = col[(size_t)r4 << 6];
        u16 v5 = col[(size_t)r5 << 6];
        u16 v6 = col[(size_t)r6 << 6];
        u16 v7 = col[(size_t)r7 << 6];
        acc += bf2f(v0); acc += bf2f(v1); acc += bf2f(v2); acc += bf2f(v3);
        acc += bf2f(v4); acc += bf2f(v5); acc += bf2f(v6); acc += bf2f(v7);
    }
    for (; j < jE; ++j) acc += bf2f(col[(size_t)csr_src[j] << 6]);

    float r = dinv[node] * acc + b[lane];
    if (GELU) {
        r = 0.5f * r * (1.0f + erff(r * 0.70710678118654752f));
        ((u16*)outraw)[((size_t)node << 6) + lane] = f2bf(r);
    } else {
        ((float*)outraw)[((size_t)node << 6) + lane] = r;
    }
}

// ---------------------------------------------------------------- launch ----
extern "C" void kernel_launch(void* const* d_in, const int* in_sizes, int n_in,
                              void* d_out, int out_size, void* d_ws, size_t ws_size,
                              hipStream_t stream) {
    const float* x  = (const float*)d_in[0];
    const int* edge = (const int*)d_in[1];           // [2, N_EDGES] int32
    const float* W1 = (const float*)d_in[2];
    const float* b1 = (const float*)d_in[3];
    const float* W2 = (const float*)d_in[4];
    const float* b2 = (const float*)d_in[5];
    float* out = (float*)d_out;                      // [N_NODES, 64] fp32

    const int* src = edge;
    const int* dst = edge + N_EDGES;

    char* ws = (char*)d_ws;
    int*   bucketCursor = (int*)(ws);                 // 196
    int*   gBase        = (int*)(ws + 1024);          // 196
    int*   row_start    = (int*)(ws + 2048);          // N+1
    float* dinv         = (float*)(ws + 402176);      // N
    int*   csr_src      = (int*)(ws + 802304);        // E  (ends 7202304)
    u16*   hsb          = (u16*)(ws + 7202304);       // N*64 bf16 = 12.8MB
    unsigned int* bins  = (unsigned int*)hsb;         // 12.54MB, dead before gemm1
    u16*   out1b        = (u16*)(ws + 20002304);      // N*64 bf16

    const int nBlkBin  = (N_EDGES + BINCHUNK - 1) / BINCHUNK;  // 391
    const int nBlkGemm = N_NODES / 16;                         // 6250
    const int nBlkAgg  = N_NODES / 4;                          // 25000

    // ---- CSR build ----
    hipMemsetAsync(bucketCursor, 0, NBUK * sizeof(int), stream);
    k_bin<<<nBlkBin, 256, 0, stream>>>(src, dst, bucketCursor, bins);
    k_bscan<<<1, 256, 0, stream>>>(bucketCursor, gBase, row_start);
    k_build<<<NBUK, 256, 0, stream>>>(bins, bucketCursor, gBase, row_start, dinv, csr_src);

    // ---- layer 1 ----
    k_gemm<128, false><<<nBlkGemm, 256, 0, stream>>>(x, W1, dinv, hsb);
    k_aggregate<true><<<nBlkAgg, 256, 0, stream>>>(hsb, csr_src, row_start, dinv, b1, out1b);

    // ---- layer 2 ----
    k_gemm<64, true><<<nBlkGemm, 256, 0, stream>>>(out1b, W2, dinv, hsb);
    k_aggregate<false><<<nBlkAgg, 256, 0, stream>>>(hsb, csr_src, row_start, dinv, b2, out);
}

// Round 6
// 196.492 us; speedup vs baseline: 4.4792x; 1.1060x over previous
//
#include <hip/hip_runtime.h>
#include <math.h>

#define N_NODES 100000
#define N_EDGES 1600000
#define NBUK 196          // dst>>9 -> 0..195 (512 nodes per bucket)
#define BCAP 16000        // entries per bucket region (mean 8192)
#define BINCHUNK 4096     // edges per k_bin block (256 thr x 16)

typedef unsigned short u16;
typedef u16 u16x4 __attribute__((ext_vector_type(4)));
typedef u16 u16x8 __attribute__((ext_vector_type(8)));
typedef short s16x8 __attribute__((ext_vector_type(8)));
typedef float f32x4 __attribute__((ext_vector_type(4)));

__device__ __forceinline__ float bf2f(u16 u) {
    union { unsigned i; float f; } v; v.i = ((unsigned)u) << 16; return v.f;
}
__device__ __forceinline__ u16 f2bf(float f) {
    union { float f; unsigned i; } v; v.f = f;
    return (u16)((v.i + 0x7FFFu + ((v.i >> 16) & 1u)) >> 16);  // RNE
}

// ---------------------------------------------------------------- binning ---
__global__ __launch_bounds__(256) void k_bin(const int* __restrict__ src,
                                             const int* __restrict__ dst,
                                             int* bucketCursor,
                                             unsigned int* __restrict__ bins) {
    __shared__ int lcnt[NBUK];
    __shared__ int lbase[NBUK];
    const int t = threadIdx.x;
    if (t < NBUK) lcnt[t] = 0;
    __syncthreads();

    const int e0 = blockIdx.x * BINCHUNK + t * 16;
    int4 s4[4], d4[4];
    int bkt[16], rnk[16];
    const bool valid = e0 < N_EDGES;   // N_EDGES % 16 == 0
    if (valid) {
        #pragma unroll
        for (int k = 0; k < 4; ++k) {
            s4[k] = *(const int4*)(src + e0 + 4 * k);
            d4[k] = *(const int4*)(dst + e0 + 4 * k);
        }
        #pragma unroll
        for (int k = 0; k < 4; ++k) {
            int dd[4] = { d4[k].x, d4[k].y, d4[k].z, d4[k].w };
            #pragma unroll
            for (int j = 0; j < 4; ++j) {
                int b = dd[j] >> 9;
                bkt[4 * k + j] = b;
                rnk[4 * k + j] = atomicAdd(&lcnt[b], 1);
            }
        }
    }
    __syncthreads();
    if (t < NBUK && lcnt[t] > 0) lbase[t] = atomicAdd(&bucketCursor[t], lcnt[t]);
    __syncthreads();
    if (valid) {
        #pragma unroll
        for (int k = 0; k < 4; ++k) {
            int ss[4] = { s4[k].x, s4[k].y, s4[k].z, s4[k].w };
            int dd[4] = { d4[k].x, d4[k].y, d4[k].z, d4[k].w };
            #pragma unroll
            for (int j = 0; j < 4; ++j) {
                int i = 4 * k + j;
                unsigned w = ((unsigned)(dd[j] & 511) << 17) | (unsigned)ss[j];
                bins[(size_t)bkt[i] * BCAP + lbase[bkt[i]] + rnk[i]] = w;
            }
        }
    }
}

// ------------------------------------------------- bucket-total scan (1 wg) -
__global__ __launch_bounds__(256) void k_bscan(const int* __restrict__ bucketCursor,
                                               int* __restrict__ gBase,
                                               int* __restrict__ row_start) {
    __shared__ int sd[256];
    const int t = threadIdx.x;
    int v = (t < NBUK) ? bucketCursor[t] : 0;
    sd[t] = v;
    __syncthreads();
    #pragma unroll
    for (int off = 1; off < 256; off <<= 1) {
        int x = (t >= off) ? sd[t - off] : 0;
        __syncthreads();
        sd[t] += x;
        __syncthreads();
    }
    if (t < NBUK) gBase[t] = (t > 0) ? sd[t - 1] : 0;
    if (t == 0) row_start[N_NODES] = N_EDGES;
}

// ------------------------------------------- per-bucket CSR build -----------
__global__ __launch_bounds__(256) void k_build(const unsigned int* __restrict__ bins,
                                               const int* __restrict__ bucketCursor,
                                               const int* __restrict__ gBase,
                                               int* __restrict__ row_start,
                                               float* __restrict__ dinv,
                                               int* __restrict__ csr_src) {
    __shared__ int cnt[512];
    __shared__ int psum[256];
    __shared__ int cur[512];
    const int b = blockIdx.x;
    const int t = threadIdx.x;
    const int bcnt = bucketCursor[b];
    const int gb = gBase[b];
    const unsigned int* mybins = bins + (size_t)b * BCAP;

    cnt[t] = 0; cnt[t + 256] = 0;
    __syncthreads();
    for (int i = t; i < bcnt; i += 256) {
        unsigned w = mybins[i];
        atomicAdd(&cnt[w >> 17], 1);
    }
    __syncthreads();
    int c0 = cnt[2 * t], c1 = cnt[2 * t + 1];
    psum[t] = c0 + c1;
    __syncthreads();
    #pragma unroll
    for (int off = 1; off < 256; off <<= 1) {
        int x = (t >= off) ? psum[t - off] : 0;
        __syncthreads();
        psum[t] += x;
        __syncthreads();
    }
    int exclPair = (t > 0) ? psum[t - 1] : 0;
    int o0 = exclPair, o1 = exclPair + c0;
    cur[2 * t] = o0; cur[2 * t + 1] = o1;
    const int nb = b << 9;
    if (nb + 2 * t < N_NODES) {
        row_start[nb + 2 * t] = gb + o0;
        dinv[nb + 2 * t] = rsqrtf((float)(c0 + 1));
    }
    if (nb + 2 * t + 1 < N_NODES) {
        row_start[nb + 2 * t + 1] = gb + o1;
        dinv[nb + 2 * t + 1] = rsqrtf((float)(c1 + 1));
    }
    __syncthreads();
    for (int i = t; i < bcnt; i += 256) {
        unsigned w = mybins[i];
        int dl = w >> 17;
        int s = (int)(w & 0x1FFFFu);
        int p = atomicAdd(&cur[dl], 1);
        csr_src[gb + p] = s;
    }
}

// ------------------------------------------------------- GEMM1 (MFMA) -------
// C = (x @ W1) * dinv, fp32-accurate via hi/lo bf16 split:
//   x@W ~= x_hi@(W_hi+W_lo) + x_lo@W_hi   (drops only ~2^-18 terms)
// Block: 256 thr = 4 waves, 64 rows x 64 cols, K=128.
// LDS tiles XOR-swizzled (byte ^= (row&7)<<4) -> conflict-free ds_read_b128.
__global__ __launch_bounds__(256) void k_gemm1(const float* __restrict__ X,
                                               const float* __restrict__ W,
                                               const float* __restrict__ dinv,
                                               u16* __restrict__ H) {
    __shared__ u16 sxh[64 * 128];   // x hi,  row-major [row][k]
    __shared__ u16 sxl[64 * 128];   // x lo
    __shared__ u16 wth[64 * 128];   // W hi, transposed [col][k]
    __shared__ u16 wtl[64 * 128];   // W lo
    const int t = threadIdx.x;
    const int blk = blockIdx.x;

    {   // stage x tile: 64 rows x 128 cols fp32 -> hi/lo bf16
        const float4* Xv = (const float4*)X;
        #pragma unroll
        for (int i = 0; i < 8; ++i) {
            int idx = i * 256 + t;           // < 2048
            int row = idx >> 5;              // 32 float4 per row
            int k4  = (idx & 31) << 2;       // float col
            int grow = blk * 64 + row;
            float4 v = make_float4(0.f, 0.f, 0.f, 0.f);
            if (grow < N_NODES) v = Xv[(size_t)grow * 32 + (idx & 31)];
            float f[4] = { v.x, v.y, v.z, v.w };
            u16x4 hv, lv;
            #pragma unroll
            for (int j = 0; j < 4; ++j) {
                u16 h = f2bf(f[j]);
                hv[j] = h;
                lv[j] = f2bf(f[j] - bf2f(h));
            }
            int byte = (row * 256 + k4 * 2) ^ ((row & 7) << 4);
            *(u16x4*)((char*)sxh + byte) = hv;
            *(u16x4*)((char*)sxl + byte) = lv;
        }
    }
    {   // stage W: 128x64 fp32, transpose to [col][k] hi/lo
        const float4* Wv = (const float4*)W;
        #pragma unroll
        for (int i = 0; i < 8; ++i) {
            int idx = i * 256 + t;           // < 2048
            int k  = idx >> 4;               // 16 float4 per row
            int c0 = (idx & 15) << 2;
            float4 v = Wv[idx];
            float f[4] = { v.x, v.y, v.z, v.w };
            #pragma unroll
            for (int j = 0; j < 4; ++j) {
                int c = c0 + j;
                int byte = (c * 256 + k * 2) ^ ((c & 7) << 4);
                u16 h = f2bf(f[j]);
                *(u16*)((char*)wth + byte) = h;
                *(u16*)((char*)wtl + byte) = f2bf(f[j] - bf2f(h));
            }
        }
    }
    __syncthreads();

    const int lane = t & 63;
    const int w    = t >> 6;
    const int l16  = lane & 15;
    const int kg   = lane >> 4;
    f32x4 acc[4];
    #pragma unroll
    for (int nt = 0; nt < 4; ++nt)
        #pragma unroll
        for (int j = 0; j < 4; ++j) acc[nt][j] = 0.f;

    const int arow = w * 16 + l16;
    const int aswz = (arow & 7) << 4;
    #pragma unroll
    for (int kt = 0; kt < 4; ++kt) {
        const int koff = kt * 64 + kg * 16;   // bytes
        s16x8 ah = *(const s16x8*)((const char*)sxh + ((arow * 256 + koff) ^ aswz));
        s16x8 al = *(const s16x8*)((const char*)sxl + ((arow * 256 + koff) ^ aswz));
        #pragma unroll
        for (int nt = 0; nt < 4; ++nt) {
            const int c = nt * 16 + l16;
            const int wb = (c * 256 + koff) ^ ((c & 7) << 4);
            s16x8 bh = *(const s16x8*)((const char*)wth + wb);
            s16x8 bl = *(const s16x8*)((const char*)wtl + wb);
            acc[nt] = __builtin_amdgcn_mfma_f32_16x16x32_bf16(ah, bh, acc[nt], 0, 0, 0);
            acc[nt] = __builtin_amdgcn_mfma_f32_16x16x32_bf16(ah, bl, acc[nt], 0, 0, 0);
            acc[nt] = __builtin_amdgcn_mfma_f32_16x16x32_bf16(al, bh, acc[nt], 0, 0, 0);
        }
    }
    const int rbase = blk * 64 + w * 16 + kg * 4;
    #pragma unroll
    for (int reg = 0; reg < 4; ++reg) {
        int row = rbase + reg;
        if (row < N_NODES) {
            float di = dinv[row];
            #pragma unroll
            for (int nt = 0; nt < 4; ++nt)
                H[(size_t)row * 64 + nt * 16 + l16] = f2bf(acc[nt][reg] * di);
        }
    }
}

// ------------------------------------------------------- GEMM2 (MFMA) -------
// Input already bf16 (exact); only W2 split hi/lo. K=64.
__global__ __launch_bounds__(256) void k_gemm2(const u16* __restrict__ Xb,
                                               const float* __restrict__ W,
                                               const float* __restrict__ dinv,
                                               u16* __restrict__ H) {
    __shared__ u16 sxb[64 * 64];
    __shared__ u16 wth[64 * 64];
    __shared__ u16 wtl[64 * 64];
    const int t = threadIdx.x;
    const int blk = blockIdx.x;

    {   // stage input tile 64x64 bf16
        const u16x8* Xv = (const u16x8*)Xb;
        #pragma unroll
        for (int i = 0; i < 2; ++i) {
            int idx = i * 256 + t;          // < 512
            int row = idx >> 3;             // 8 vec per row
            int k0  = (idx & 7) << 3;
            int grow = blk * 64 + row;
            u16x8 v;
            #pragma unroll
            for (int j = 0; j < 8; ++j) v[j] = 0;
            if (grow < N_NODES) v = Xv[(size_t)grow * 8 + (idx & 7)];
            int byte = (row * 128 + k0 * 2) ^ ((row & 7) << 4);
            *(u16x8*)((char*)sxb + byte) = v;
        }
    }
    {   // stage W2 64x64 fp32 transposed hi/lo
        const float4* Wv = (const float4*)W;
        #pragma unroll
        for (int i = 0; i < 4; ++i) {
            int idx = i * 256 + t;          // < 1024
            int k  = idx >> 4;
            int c0 = (idx & 15) << 2;
            float4 v = Wv[idx];
            float f[4] = { v.x, v.y, v.z, v.w };
            #pragma unroll
            for (int j = 0; j < 4; ++j) {
                int c = c0 + j;
                int byte = (c * 128 + k * 2) ^ ((c & 7) << 4);
                u16 h = f2bf(f[j]);
                *(u16*)((char*)wth + byte) = h;
                *(u16*)((char*)wtl + byte) = f2bf(f[j] - bf2f(h));
            }
        }
    }
    __syncthreads();

    const int lane = t & 63;
    const int w    = t >> 6;
    const int l16  = lane & 15;
    const int kg   = lane >> 4;
    f32x4 acc[4];
    #pragma unroll
    for (int nt = 0; nt < 4; ++nt)
        #pragma unroll
        for (int j = 0; j < 4; ++j) acc[nt][j] = 0.f;

    const int arow = w * 16 + l16;
    const int aswz = (arow & 7) << 4;
    #pragma unroll
    for (int kt = 0; kt < 2; ++kt) {
        const int koff = kt * 64 + kg * 16;
        s16x8 a = *(const s16x8*)((const char*)sxb + ((arow * 128 + koff) ^ aswz));
        #pragma unroll
        for (int nt = 0; nt < 4; ++nt) {
            const int c = nt * 16 + l16;
            const int wb = (c * 128 + koff) ^ ((c & 7) << 4);
            s16x8 bh = *(const s16x8*)((const char*)wth + wb);
            s16x8 bl = *(const s16x8*)((const char*)wtl + wb);
            acc[nt] = __builtin_amdgcn_mfma_f32_16x16x32_bf16(a, bh, acc[nt], 0, 0, 0);
            acc[nt] = __builtin_amdgcn_mfma_f32_16x16x32_bf16(a, bl, acc[nt], 0, 0, 0);
        }
    }
    const int rbase = blk * 64 + w * 16 + kg * 4;
    #pragma unroll
    for (int reg = 0; reg < 4; ++reg) {
        int row = rbase + reg;
        if (row < N_NODES) {
            float di = dinv[row];
            #pragma unroll
            for (int nt = 0; nt < 4; ++nt)
                H[(size_t)row * 64 + nt * 16 + l16] = f2bf(acc[nt][reg] * di);
        }
    }
}

// ---------------------------------------------------------------- aggregate -
// One wave per node; lane = feature column. Per edge: one 2B load per lane
// (128 B contiguous per wave), cvt, add. No cross-lane reduce.
template <bool GELU>
__global__ __launch_bounds__(256) void k_aggregate(const u16* __restrict__ hs,
                                                   const int* __restrict__ csr_src,
                                                   const int* __restrict__ row_start,
                                                   const float* __restrict__ dinv,
                                                   const float* __restrict__ b,
                                                   void* __restrict__ outraw) {
    const int node = __builtin_amdgcn_readfirstlane(blockIdx.x * 4 + (threadIdx.x >> 6));
    const int lane = threadIdx.x & 63;
    const u16* __restrict__ col = hs + lane;

    const int jS = row_start[node];
    const int jE = row_start[node + 1];
    float acc = bf2f(col[(size_t)node << 6]);   // self-loop
    int j = jS;
    for (; j + 8 <= jE; j += 8) {
        int r0 = csr_src[j + 0], r1 = csr_src[j + 1];
        int r2 = csr_src[j + 2], r3 = csr_src[j + 3];
        int r4 = csr_src[j + 4], r5 = csr_src[j + 5];
        int r6 = csr_src[j + 6], r7 = csr_src[j + 7];
        u16 v0 = col[(size_t)r0 << 6];
        u16 v1 = col[(size_t)r1 << 6];
        u16 v2 = col[(size_t)r2 << 6];
        u16 v3 = col[(size_t)r3 << 6];
        u16 v4 = col[(size_t)r4 << 6];
        u16 v5 = col[(size_t)r5 << 6];
        u16 v6 = col[(size_t)r6 << 6];
        u16 v7 = col[(size_t)r7 << 6];
        acc += bf2f(v0); acc += bf2f(v1); acc += bf2f(v2); acc += bf2f(v3);
        acc += bf2f(v4); acc += bf2f(v5); acc += bf2f(v6); acc += bf2f(v7);
    }
    for (; j < jE; ++j) acc += bf2f(col[(size_t)csr_src[j] << 6]);

    float r = dinv[node] * acc + b[lane];
    if (GELU) {
        r = 0.5f * r * (1.0f + erff(r * 0.70710678118654752f));
        ((u16*)outraw)[((size_t)node << 6) + lane] = f2bf(r);
    } else {
        ((float*)outraw)[((size_t)node << 6) + lane] = r;
    }
}

// ---------------------------------------------------------------- launch ----
extern "C" void kernel_launch(void* const* d_in, const int* in_sizes, int n_in,
                              void* d_out, int out_size, void* d_ws, size_t ws_size,
                              hipStream_t stream) {
    const float* x  = (const float*)d_in[0];
    const int* edge = (const int*)d_in[1];           // [2, N_EDGES] int32
    const float* W1 = (const float*)d_in[2];
    const float* b1 = (const float*)d_in[3];
    const float* W2 = (const float*)d_in[4];
    const float* b2 = (const float*)d_in[5];
    float* out = (float*)d_out;                      // [N_NODES, 64] fp32

    const int* src = edge;
    const int* dst = edge + N_EDGES;

    char* ws = (char*)d_ws;
    int*   bucketCursor = (int*)(ws);                 // 196
    int*   gBase        = (int*)(ws + 1024);          // 196
    int*   row_start    = (int*)(ws + 2048);          // N+1
    float* dinv         = (float*)(ws + 402176);      // N
    int*   csr_src      = (int*)(ws + 802304);        // E  (ends 7202304)
    u16*   hsb          = (u16*)(ws + 7202304);       // N*64 bf16 = 12.8MB
    unsigned int* bins  = (unsigned int*)hsb;         // 12.54MB, dead before gemm1
    u16*   out1b        = (u16*)(ws + 20002304);      // N*64 bf16

    const int nBlkBin  = (N_EDGES + BINCHUNK - 1) / BINCHUNK;  // 391
    const int nBlkGemm = (N_NODES + 63) / 64;                  // 1563
    const int nBlkAgg  = N_NODES / 4;                          // 25000

    // ---- CSR build ----
    hipMemsetAsync(bucketCursor, 0, NBUK * sizeof(int), stream);
    k_bin<<<nBlkBin, 256, 0, stream>>>(src, dst, bucketCursor, bins);
    k_bscan<<<1, 256, 0, stream>>>(bucketCursor, gBase, row_start);
    k_build<<<NBUK, 256, 0, stream>>>(bins, bucketCursor, gBase, row_start, dinv, csr_src);

    // ---- layer 1 ----
    k_gemm1<<<nBlkGemm, 256, 0, stream>>>(x, W1, dinv, hsb);
    k_aggregate<true><<<nBlkAgg, 256, 0, stream>>>(hsb, csr_src, row_start, dinv, b1, out1b);

    // ---- layer 2 ----
    k_gemm2<<<nBlkGemm, 256, 0, stream>>>(out1b, W2, dinv, hsb);
    k_aggregate<false><<<nBlkAgg, 256, 0, stream>>>(hsb, csr_src, row_start, dinv, b2, out);
}

// Round 7
// 188.539 us; speedup vs baseline: 4.6682x; 1.0422x over previous
//
#include <hip/hip_runtime.h>
#include <math.h>

#define N_NODES 100000
#define N_EDGES 1600000
#define NBUK 196          // dst>>9 -> 0..195 (512 nodes per bucket)
#define BCAP 16000        // entries per bucket region (mean 8192)
#define BINCHUNK 4096     // edges per k_bin block (256 thr x 16)

typedef unsigned short u16;
typedef u16 u16x4 __attribute__((ext_vector_type(4)));
typedef u16 u16x8 __attribute__((ext_vector_type(8)));
typedef short s16x8 __attribute__((ext_vector_type(8)));
typedef float f32x4 __attribute__((ext_vector_type(4)));

__device__ __forceinline__ float bf2f(u16 u) {
    union { unsigned i; float f; } v; v.i = ((unsigned)u) << 16; return v.f;
}
__device__ __forceinline__ u16 f2bf(float f) {
    union { float f; unsigned i; } v; v.f = f;
    return (u16)((v.i + 0x7FFFu + ((v.i >> 16) & 1u)) >> 16);  // RNE
}

// ---------------------------------------------------------------- binning ---
__global__ __launch_bounds__(256) void k_bin(const int* __restrict__ src,
                                             const int* __restrict__ dst,
                                             int* bucketCursor,
                                             unsigned int* __restrict__ bins) {
    __shared__ int lcnt[NBUK];
    __shared__ int lbase[NBUK];
    const int t = threadIdx.x;
    if (t < NBUK) lcnt[t] = 0;
    __syncthreads();

    const int e0 = blockIdx.x * BINCHUNK + t * 16;
    int4 s4[4], d4[4];
    int bkt[16], rnk[16];
    const bool valid = e0 < N_EDGES;   // N_EDGES % 16 == 0
    if (valid) {
        #pragma unroll
        for (int k = 0; k < 4; ++k) {
            s4[k] = *(const int4*)(src + e0 + 4 * k);
            d4[k] = *(const int4*)(dst + e0 + 4 * k);
        }
        #pragma unroll
        for (int k = 0; k < 4; ++k) {
            int dd[4] = { d4[k].x, d4[k].y, d4[k].z, d4[k].w };
            #pragma unroll
            for (int j = 0; j < 4; ++j) {
                int b = dd[j] >> 9;
                bkt[4 * k + j] = b;
                rnk[4 * k + j] = atomicAdd(&lcnt[b], 1);
            }
        }
    }
    __syncthreads();
    if (t < NBUK && lcnt[t] > 0) lbase[t] = atomicAdd(&bucketCursor[t], lcnt[t]);
    __syncthreads();
    if (valid) {
        #pragma unroll
        for (int k = 0; k < 4; ++k) {
            int ss[4] = { s4[k].x, s4[k].y, s4[k].z, s4[k].w };
            int dd[4] = { d4[k].x, d4[k].y, d4[k].z, d4[k].w };
            #pragma unroll
            for (int j = 0; j < 4; ++j) {
                int i = 4 * k + j;
                unsigned w = ((unsigned)(dd[j] & 511) << 17) | (unsigned)ss[j];
                bins[(size_t)bkt[i] * BCAP + lbase[bkt[i]] + rnk[i]] = w;
            }
        }
    }
}

// ------------------------------------------------- bucket-total scan (1 wg) -
__global__ __launch_bounds__(256) void k_bscan(const int* __restrict__ bucketCursor,
                                               int* __restrict__ gBase,
                                               int* __restrict__ row_start) {
    __shared__ int sd[256];
    const int t = threadIdx.x;
    int v = (t < NBUK) ? bucketCursor[t] : 0;
    sd[t] = v;
    __syncthreads();
    #pragma unroll
    for (int off = 1; off < 256; off <<= 1) {
        int x = (t >= off) ? sd[t - off] : 0;
        __syncthreads();
        sd[t] += x;
        __syncthreads();
    }
    if (t < NBUK) gBase[t] = (t > 0) ? sd[t - 1] : 0;
    if (t == 0) row_start[N_NODES] = N_EDGES;
}

// ------------------------------------------- per-bucket CSR build -----------
__global__ __launch_bounds__(256) void k_build(const unsigned int* __restrict__ bins,
                                               const int* __restrict__ bucketCursor,
                                               const int* __restrict__ gBase,
                                               int* __restrict__ row_start,
                                               float* __restrict__ dinv,
                                               int* __restrict__ csr_src) {
    __shared__ int cnt[512];
    __shared__ int psum[256];
    __shared__ int cur[512];
    const int b = blockIdx.x;
    const int t = threadIdx.x;
    const int bcnt = bucketCursor[b];
    const int gb = gBase[b];
    const unsigned int* mybins = bins + (size_t)b * BCAP;

    cnt[t] = 0; cnt[t + 256] = 0;
    __syncthreads();
    for (int i = t; i < bcnt; i += 256) {
        unsigned w = mybins[i];
        atomicAdd(&cnt[w >> 17], 1);
    }
    __syncthreads();
    int c0 = cnt[2 * t], c1 = cnt[2 * t + 1];
    psum[t] = c0 + c1;
    __syncthreads();
    #pragma unroll
    for (int off = 1; off < 256; off <<= 1) {
        int x = (t >= off) ? psum[t - off] : 0;
        __syncthreads();
        psum[t] += x;
        __syncthreads();
    }
    int exclPair = (t > 0) ? psum[t - 1] : 0;
    int o0 = exclPair, o1 = exclPair + c0;
    cur[2 * t] = o0; cur[2 * t + 1] = o1;
    const int nb = b << 9;
    if (nb + 2 * t < N_NODES) {
        row_start[nb + 2 * t] = gb + o0;
        dinv[nb + 2 * t] = rsqrtf((float)(c0 + 1));
    }
    if (nb + 2 * t + 1 < N_NODES) {
        row_start[nb + 2 * t + 1] = gb + o1;
        dinv[nb + 2 * t + 1] = rsqrtf((float)(c1 + 1));
    }
    __syncthreads();
    for (int i = t; i < bcnt; i += 256) {
        unsigned w = mybins[i];
        int dl = w >> 17;
        int s = (int)(w & 0x1FFFFu);
        int p = atomicAdd(&cur[dl], 1);
        csr_src[gb + p] = s;
    }
}

// ------------------------------------------------------- GEMM1 (MFMA) -------
// C = (x @ W1) * dinv via hi/lo bf16 split. Rows >= N_NODES get zeros (the
// aggregate's dummy-gather zero row lives at row N_NODES).
__global__ __launch_bounds__(256) void k_gemm1(const float* __restrict__ X,
                                               const float* __restrict__ W,
                                               const float* __restrict__ dinv,
                                               u16* __restrict__ H) {
    __shared__ u16 sxh[64 * 128];
    __shared__ u16 sxl[64 * 128];
    __shared__ u16 wth[64 * 128];
    __shared__ u16 wtl[64 * 128];
    const int t = threadIdx.x;
    const int blk = blockIdx.x;

    {
        const float4* Xv = (const float4*)X;
        #pragma unroll
        for (int i = 0; i < 8; ++i) {
            int idx = i * 256 + t;
            int row = idx >> 5;
            int k4  = (idx & 31) << 2;
            int grow = blk * 64 + row;
            float4 v = make_float4(0.f, 0.f, 0.f, 0.f);
            if (grow < N_NODES) v = Xv[(size_t)grow * 32 + (idx & 31)];
            float f[4] = { v.x, v.y, v.z, v.w };
            u16x4 hv, lv;
            #pragma unroll
            for (int j = 0; j < 4; ++j) {
                u16 h = f2bf(f[j]);
                hv[j] = h;
                lv[j] = f2bf(f[j] - bf2f(h));
            }
            int byte = (row * 256 + k4 * 2) ^ ((row & 7) << 4);
            *(u16x4*)((char*)sxh + byte) = hv;
            *(u16x4*)((char*)sxl + byte) = lv;
        }
    }
    {
        const float4* Wv = (const float4*)W;
        #pragma unroll
        for (int i = 0; i < 8; ++i) {
            int idx = i * 256 + t;
            int k  = idx >> 4;
            int c0 = (idx & 15) << 2;
            float4 v = Wv[idx];
            float f[4] = { v.x, v.y, v.z, v.w };
            #pragma unroll
            for (int j = 0; j < 4; ++j) {
                int c = c0 + j;
                int byte = (c * 256 + k * 2) ^ ((c & 7) << 4);
                u16 h = f2bf(f[j]);
                *(u16*)((char*)wth + byte) = h;
                *(u16*)((char*)wtl + byte) = f2bf(f[j] - bf2f(h));
            }
        }
    }
    __syncthreads();

    const int lane = t & 63;
    const int w    = t >> 6;
    const int l16  = lane & 15;
    const int kg   = lane >> 4;
    f32x4 acc[4];
    #pragma unroll
    for (int nt = 0; nt < 4; ++nt)
        #pragma unroll
        for (int j = 0; j < 4; ++j) acc[nt][j] = 0.f;

    const int arow = w * 16 + l16;
    const int aswz = (arow & 7) << 4;
    #pragma unroll
    for (int kt = 0; kt < 4; ++kt) {
        const int koff = kt * 64 + kg * 16;
        s16x8 ah = *(const s16x8*)((const char*)sxh + ((arow * 256 + koff) ^ aswz));
        s16x8 al = *(const s16x8*)((const char*)sxl + ((arow * 256 + koff) ^ aswz));
        #pragma unroll
        for (int nt = 0; nt < 4; ++nt) {
            const int c = nt * 16 + l16;
            const int wb = (c * 256 + koff) ^ ((c & 7) << 4);
            s16x8 bh = *(const s16x8*)((const char*)wth + wb);
            s16x8 bl = *(const s16x8*)((const char*)wtl + wb);
            acc[nt] = __builtin_amdgcn_mfma_f32_16x16x32_bf16(ah, bh, acc[nt], 0, 0, 0);
            acc[nt] = __builtin_amdgcn_mfma_f32_16x16x32_bf16(ah, bl, acc[nt], 0, 0, 0);
            acc[nt] = __builtin_amdgcn_mfma_f32_16x16x32_bf16(al, bh, acc[nt], 0, 0, 0);
        }
    }
    const int rbase = blk * 64 + w * 16 + kg * 4;
    #pragma unroll
    for (int reg = 0; reg < 4; ++reg) {
        int row = rbase + reg;
        float di = (row < N_NODES) ? dinv[row] : 0.f;
        #pragma unroll
        for (int nt = 0; nt < 4; ++nt)
            H[(size_t)row * 64 + nt * 16 + l16] = f2bf(acc[nt][reg] * di);
    }
}

// ------------------------------------------------------- GEMM2 (MFMA) -------
__global__ __launch_bounds__(256) void k_gemm2(const u16* __restrict__ Xb,
                                               const float* __restrict__ W,
                                               const float* __restrict__ dinv,
                                               u16* __restrict__ H) {
    __shared__ u16 sxb[64 * 64];
    __shared__ u16 wth[64 * 64];
    __shared__ u16 wtl[64 * 64];
    const int t = threadIdx.x;
    const int blk = blockIdx.x;

    {
        const u16x8* Xv = (const u16x8*)Xb;
        #pragma unroll
        for (int i = 0; i < 2; ++i) {
            int idx = i * 256 + t;
            int row = idx >> 3;
            int k0  = (idx & 7) << 3;
            int grow = blk * 64 + row;
            u16x8 v;
            #pragma unroll
            for (int j = 0; j < 8; ++j) v[j] = 0;
            if (grow < N_NODES) v = Xv[(size_t)grow * 8 + (idx & 7)];
            int byte = (row * 128 + k0 * 2) ^ ((row & 7) << 4);
            *(u16x8*)((char*)sxb + byte) = v;
        }
    }
    {
        const float4* Wv = (const float4*)W;
        #pragma unroll
        for (int i = 0; i < 4; ++i) {
            int idx = i * 256 + t;
            int k  = idx >> 4;
            int c0 = (idx & 15) << 2;
            float4 v = Wv[idx];
            float f[4] = { v.x, v.y, v.z, v.w };
            #pragma unroll
            for (int j = 0; j < 4; ++j) {
                int c = c0 + j;
                int byte = (c * 128 + k * 2) ^ ((c & 7) << 4);
                u16 h = f2bf(f[j]);
                *(u16*)((char*)wth + byte) = h;
                *(u16*)((char*)wtl + byte) = f2bf(f[j] - bf2f(h));
            }
        }
    }
    __syncthreads();

    const int lane = t & 63;
    const int w    = t >> 6;
    const int l16  = lane & 15;
    const int kg   = lane >> 4;
    f32x4 acc[4];
    #pragma unroll
    for (int nt = 0; nt < 4; ++nt)
        #pragma unroll
        for (int j = 0; j < 4; ++j) acc[nt][j] = 0.f;

    const int arow = w * 16 + l16;
    const int aswz = (arow & 7) << 4;
    #pragma unroll
    for (int kt = 0; kt < 2; ++kt) {
        const int koff = kt * 64 + kg * 16;
        s16x8 a = *(const s16x8*)((const char*)sxb + ((arow * 128 + koff) ^ aswz));
        #pragma unroll
        for (int nt = 0; nt < 4; ++nt) {
            const int c = nt * 16 + l16;
            const int wb = (c * 128 + koff) ^ ((c & 7) << 4);
            s16x8 bh = *(const s16x8*)((const char*)wth + wb);
            s16x8 bl = *(const s16x8*)((const char*)wtl + wb);
            acc[nt] = __builtin_amdgcn_mfma_f32_16x16x32_bf16(a, bh, acc[nt], 0, 0, 0);
            acc[nt] = __builtin_amdgcn_mfma_f32_16x16x32_bf16(a, bl, acc[nt], 0, 0, 0);
        }
    }
    const int rbase = blk * 64 + w * 16 + kg * 4;
    #pragma unroll
    for (int reg = 0; reg < 4; ++reg) {
        int row = rbase + reg;
        float di = (row < N_NODES) ? dinv[row] : 0.f;
        #pragma unroll
        for (int nt = 0; nt < 4; ++nt)
            H[(size_t)row * 64 + nt * 16 + l16] = f2bf(acc[nt][reg] * di);
    }
}

// ---------------------------------------------------------------- aggregate -
// 4 nodes/block (1/wave), lane = feature column. CSR indices staged into LDS
// slots of 32 per node (padded with the zero row N_NODES), so the gather loop
// has NO global index loads and NO predication: ds_read_b128 pairs feed 8
// independent 2B gathers per batch. deg>32 nodes (rare) use a global fallback.
template <bool GELU>
__global__ __launch_bounds__(256) void k_aggregate(const u16* __restrict__ hs,
                                                   const int* __restrict__ csr_src,
                                                   const int* __restrict__ row_start,
                                                   const float* __restrict__ dinv,
                                                   const float* __restrict__ b,
                                                   void* __restrict__ outraw) {
    __shared__ int sIdx[128];
    __shared__ int sRS[5];
    const int t = threadIdx.x;
    const int n0 = blockIdx.x << 2;
    if (t < 5) sRS[t] = row_start[n0 + t];
    __syncthreads();
    if (t < 128) {
        int k = t >> 5, o = t & 31;
        int jsk = sRS[k];
        int degk = sRS[k + 1] - jsk;
        sIdx[t] = (o < degk) ? csr_src[jsk + o] : N_NODES;   // pad -> zero row
    }
    __syncthreads();

    const int w    = t >> 6;
    const int lane = t & 63;
    const int node = n0 + w;
    const int deg  = sRS[w + 1] - sRS[w];
    const size_t laneB = (size_t)(lane << 1);
    const char* hsB = (const char*)hs;

    float acc = bf2f(hs[((size_t)node << 6) + lane]);   // self-loop

    if (deg <= 32) {
        const int4* s4 = (const int4*)(sIdx + (w << 5));
#define GATH8(B) { \
        int4 qa = s4[2*(B)], qb = s4[2*(B)+1]; \
        u16 v0 = *(const u16*)(hsB + (((size_t)qa.x << 7) + laneB)); \
        u16 v1 = *(const u16*)(hsB + (((size_t)qa.y << 7) + laneB)); \
        u16 v2 = *(const u16*)(hsB + (((size_t)qa.z << 7) + laneB)); \
        u16 v3 = *(const u16*)(hsB + (((size_t)qa.w << 7) + laneB)); \
        u16 v4 = *(const u16*)(hsB + (((size_t)qb.x << 7) + laneB)); \
        u16 v5 = *(const u16*)(hsB + (((size_t)qb.y << 7) + laneB)); \
        u16 v6 = *(const u16*)(hsB + (((size_t)qb.z << 7) + laneB)); \
        u16 v7 = *(const u16*)(hsB + (((size_t)qb.w << 7) + laneB)); \
        acc += bf2f(v0); acc += bf2f(v1); acc += bf2f(v2); acc += bf2f(v3); \
        acc += bf2f(v4); acc += bf2f(v5); acc += bf2f(v6); acc += bf2f(v7); }
        if (deg > 0)  GATH8(0)
        if (deg > 8)  GATH8(1)
        if (deg > 16) GATH8(2)
        if (deg > 24) GATH8(3)
#undef GATH8
    } else {
        const int jS = sRS[w];
        const int jE = jS + deg;
        int j = jS;
        for (; j + 8 <= jE; j += 8) {
            int r0 = csr_src[j + 0], r1 = csr_src[j + 1];
            int r2 = csr_src[j + 2], r3 = csr_src[j + 3];
            int r4 = csr_src[j + 4], r5 = csr_src[j + 5];
            int r6 = csr_src[j + 6], r7 = csr_src[j + 7];
            u16 v0 = *(const u16*)(hsB + (((size_t)r0 << 7) + laneB));
            u16 v1 = *(const u16*)(hsB + (((size_t)r1 << 7) + laneB));
            u16 v2 = *(const u16*)(hsB + (((size_t)r2 << 7) + laneB));
            u16 v3 = *(const u16*)(hsB + (((size_t)r3 << 7) + laneB));
            u16 v4 = *(const u16*)(hsB + (((size_t)r4 << 7) + laneB));
            u16 v5 = *(const u16*)(hsB + (((size_t)r5 << 7) + laneB));
            u16 v6 = *(const u16*)(hsB + (((size_t)r6 << 7) + laneB));
            u16 v7 = *(const u16*)(hsB + (((size_t)r7 << 7) + laneB));
            acc += bf2f(v0); acc += bf2f(v1); acc += bf2f(v2); acc += bf2f(v3);
            acc += bf2f(v4); acc += bf2f(v5); acc += bf2f(v6); acc += bf2f(v7);
        }
        for (; j < jE; ++j)
            acc += bf2f(*(const u16*)(hsB + (((size_t)csr_src[j] << 7) + laneB)));
    }

    float r = dinv[node] * acc + b[lane];
    if (GELU) {
        r = 0.5f * r * (1.0f + erff(r * 0.70710678118654752f));
        ((u16*)outraw)[((size_t)node << 6) + lane] = f2bf(r);
    } else {
        ((float*)outraw)[((size_t)node << 6) + lane] = r;
    }
}

// ---------------------------------------------------------------- launch ----
extern "C" void kernel_launch(void* const* d_in, const int* in_sizes, int n_in,
                              void* d_out, int out_size, void* d_ws, size_t ws_size,
                              hipStream_t stream) {
    const float* x  = (const float*)d_in[0];
    const int* edge = (const int*)d_in[1];           // [2, N_EDGES] int32
    const float* W1 = (const float*)d_in[2];
    const float* b1 = (const float*)d_in[3];
    const float* W2 = (const float*)d_in[4];
    const float* b2 = (const float*)d_in[5];
    float* out = (float*)d_out;                      // [N_NODES, 64] fp32

    const int* src = edge;
    const int* dst = edge + N_EDGES;

    char* ws = (char*)d_ws;
    int*   bucketCursor = (int*)(ws);                 // 196
    int*   gBase        = (int*)(ws + 1024);          // 196
    int*   row_start    = (int*)(ws + 2048);          // N+1
    float* dinv         = (float*)(ws + 402176);      // N
    int*   csr_src      = (int*)(ws + 802304);        // E  (ends 7202304)
    u16*   hsb          = (u16*)(ws + 7202304);       // 100032 rows bf16 (ends 20006400)
    unsigned int* bins  = (unsigned int*)hsb;         // 12.54MB, dead before gemm1
    u16*   out1b        = (u16*)(ws + 20006400);      // 100032 rows bf16

    const int nBlkBin  = (N_EDGES + BINCHUNK - 1) / BINCHUNK;  // 391
    const int nBlkGemm = (N_NODES + 63) / 64;                  // 1563 (covers 100032)
    const int nBlkAgg  = N_NODES / 4;                          // 25000

    // ---- CSR build ----
    hipMemsetAsync(bucketCursor, 0, NBUK * sizeof(int), stream);
    k_bin<<<nBlkBin, 256, 0, stream>>>(src, dst, bucketCursor, bins);
    k_bscan<<<1, 256, 0, stream>>>(bucketCursor, gBase, row_start);
    k_build<<<NBUK, 256, 0, stream>>>(bins, bucketCursor, gBase, row_start, dinv, csr_src);

    // ---- layer 1 ----
    k_gemm1<<<nBlkGemm, 256, 0, stream>>>(x, W1, dinv, hsb);
    k_aggregate<true><<<nBlkAgg, 256, 0, stream>>>(hsb, csr_src, row_start, dinv, b1, out1b);

    // ---- layer 2 ----
    k_gemm2<<<nBlkGemm, 256, 0, stream>>>(out1b, W2, dinv, hsb);
    k_aggregate<false><<<nBlkAgg, 256, 0, stream>>>(hsb, csr_src, row_start, dinv, b2, out);
}